// Round 15
// baseline (180.426 us; speedup 1.0000x reference)
//
#include <hip/hip_runtime.h>
#include <hip/hip_bf16.h>
#include <hip/hip_cooperative_groups.h>

namespace cg = cooperative_groups;

#define BB 2
#define NN 4096
#define KNN 16
#define CC 64
#define CO 128
#define ROWS (BB*NN*KNN)   // 131072
#define K0P 96             // padded/permuted K for layer 0
#define NSLOT 16
#define WST 136            // 128 + 8 pad (bf16 elems), for fallback LDS staging

// k_pre block ranges
#define PRE_PREP 112       // covers i < 28672
#define PRE_PROD 512       // 131072 float4 elems
#define PRE_BALL 2048      // 8192 anchors / 4 per block

typedef __attribute__((ext_vector_type(8))) short bf16x8;
typedef __attribute__((ext_vector_type(4))) float f32x4;

__device__ __forceinline__ float bf2f(unsigned short u) {
    return __uint_as_float(((unsigned)u) << 16);
}
__device__ __forceinline__ unsigned short f2bf(float f) {
    __hip_bfloat16 h = __float2bfloat16(f);
    return *reinterpret_cast<unsigned short*>(&h);
}

union U16B { uint4 v; unsigned short us[8]; };

// Y-tile LDS addressing: row stride 256B (128 bf16), XOR swizzle of 16B slot by row
__device__ __forceinline__ int yoff(int row, int byteInRow) {
    return row * 256 + (byteInRow ^ ((row & 7) << 4));
}

// ======================= k_pre: stats-zero + W0 permute/cvt + W2 cvt + prod + ball =======================
__global__ __launch_bounds__(256) void k_pre(const float* __restrict__ anchor,
                                             const float* __restrict__ neighbor,
                                             const float* __restrict__ feat,
                                             const float* __restrict__ nfeat,
                                             const float* __restrict__ W0,
                                             const float* __restrict__ W2,
                                             short* __restrict__ W0p,
                                             short* __restrict__ W2p,
                                             float* __restrict__ stats,
                                             int* __restrict__ idx,
                                             unsigned short* __restrict__ P) {
    int blk = blockIdx.x;
    int t = threadIdx.x;
    if (blk < PRE_PREP) {
        int i = blk * 256 + t;
        if (i < 3 * NSLOT * CO * 2) stats[i] = 0.0f;          // 12288 floats
        if (i < 128 * K0P) {                                   // 12288
            int o = i / K0P, k = i - o * K0P;
            float v;
            if (k < 64)      v = W0[o * 67 + 3 + k];
            else if (k < 67) v = W0[o * 67 + (k - 64)];
            else             v = 0.0f;
            W0p[i] = (short)f2bf(v);
        } else if (i < 128 * K0P + 16384) {
            int e = i - 128 * K0P;
            W2p[e] = (short)f2bf(W2[e]);
        }
    } else if (blk < PRE_PREP + PRE_PROD) {
        int i = (blk - PRE_PREP) * 256 + t;                    // < 131072
        float4 a = ((const float4*)feat)[i];
        float4 b = ((const float4*)nfeat)[i];
        ushort4 r;
        r.x = f2bf(__fmul_rn(a.x, b.x));
        r.y = f2bf(__fmul_rn(a.y, b.y));
        r.z = f2bf(__fmul_rn(a.z, b.z));
        r.w = f2bf(__fmul_rn(a.w, b.w));
        ((ushort4*)P)[i] = r;
    } else {
        // ball query: one anchor per wave, ballot ordered extraction
        int lane = t & 63;
        int an = (blk - PRE_PREP - PRE_PROD) * 4 + (t >> 6);   // 0..8191
        int b = an >> 12;
        const float* nb = neighbor + (size_t)b * NN * 3;

        float ax = anchor[an * 3 + 0];
        float ay = anchor[an * 3 + 1];
        float az = anchor[an * 3 + 2];

        unsigned long long lmask = (lane == 63) ? 0xFFFFFFFFFFFFFFFFull >> 1
                                                : ((1ull << lane) - 1ull);
        int cnt = 0;
        int firstIdx = -1;
        int* myout = idx + (size_t)an * KNN;

        for (int chunk = 0; chunk < NN / 64 && cnt < KNN; ++chunk) {
            int j = chunk * 64 + lane;
            float dx = __fsub_rn(ax, nb[j * 3 + 0]);
            float dy = __fsub_rn(ay, nb[j * 3 + 1]);
            float dz = __fsub_rn(az, nb[j * 3 + 2]);
            float d2 = __fadd_rn(__fadd_rn(__fmul_rn(dx, dx), __fmul_rn(dy, dy)),
                                 __fmul_rn(dz, dz));
            bool hit = d2 < 1.0f;
            unsigned long long m = __ballot(hit);
            if (m) {
                int pos = cnt + __popcll(m & lmask);
                if (hit && pos < KNN) myout[pos] = j;
                if (firstIdx < 0) firstIdx = chunk * 64 + (__ffsll((long long)m) - 1);
                cnt += __popcll(m);
            }
        }
        if (cnt < KNN) {
            int f = (firstIdx < 0) ? 0 : firstIdx;
            if (lane >= cnt && lane < KNN) myout[lane] = f;
        }
    }
}

// gather X fragments for GEMM0 (xf[2][3])
__device__ __forceinline__ void gather_xf(int rowBase, int w, int lm, int g,
                                          const float* anchor, const float* neighbor,
                                          const unsigned short* P, const int* idx,
                                          bf16x8 xf[2][3]) {
#pragma unroll
    for (int i = 0; i < 2; ++i) {
        int r = rowBase + w * 32 + i * 16 + lm;
        int bn = r >> 4;
        int bb = r >> 16;
        int j = idx[r];
        const unsigned short* Prow = P + ((size_t)(bb << 12) + j) * CC;
        xf[i][0] = *(const bf16x8*)(Prow + g * 8);
        xf[i][1] = *(const bf16x8*)(Prow + 32 + g * 8);
        bf16x8 x2 = {0, 0, 0, 0, 0, 0, 0, 0};
        if (g == 0) {
            const float* nbr = neighbor + ((size_t)(bb << 12) + j) * 3;
            float dx = __fsub_rn(anchor[bn * 3 + 0], nbr[0]);
            float dy = __fsub_rn(anchor[bn * 3 + 1], nbr[1]);
            float dz = __fsub_rn(anchor[bn * 3 + 2], nbr[2]);
            x2[0] = (short)f2bf(dx);
            x2[1] = (short)f2bf(dy);
            x2[2] = (short)f2bf(dz);
        }
        xf[i][2] = x2;
    }
}

// ======================= k_mega (cooperative, 256 blocks x 4 tiles): G0|fold|G1|G2 ============
__global__ __launch_bounds__(256, 1) void k_mega(const float* __restrict__ anchor,
                                                 const float* __restrict__ neighbor,
                                                 const unsigned short* __restrict__ P,
                                                 const int* __restrict__ idx,
                                                 const short* __restrict__ W0p,
                                                 const float* __restrict__ W1,
                                                 const short* __restrict__ W2p,
                                                 const float* __restrict__ gamma0,
                                                 const float* __restrict__ beta0,
                                                 const float* __restrict__ gamma1,
                                                 const float* __restrict__ beta1,
                                                 short* __restrict__ W1s,
                                                 float* __restrict__ bias1,
                                                 float* __restrict__ stats0,
                                                 float* __restrict__ stats1,
                                                 float* __restrict__ stats2,
                                                 float* __restrict__ maxh,
                                                 float* __restrict__ minh) {
    cg::grid_group gg = cg::this_grid();
    __shared__ alignas(16) short Y[4][128 * 128];   // 128 KB: y0, then raw h1
    __shared__ float sred[CO * 2];
    __shared__ float ssc[CO];
    __shared__ float ssh[CO];

    int t = threadIdx.x;
    int blockRow = blockIdx.x * 512;
    int lane = t & 63, w = t >> 6;
    int lm = lane & 15, g = lane >> 4;
    int slot = blockIdx.x & (NSLOT - 1);
    f32x4 zero = {0.f, 0.f, 0.f, 0.f};

    // ================= Phase 0: G0 all 4 tiles -> Y + stats0 =================
    sred[t] = 0.0f;
    __syncthreads();
    for (int tt = 0; tt < 4; ++tt) {
        int rowBase = blockRow + tt * 128;
        bf16x8 xf[2][3];
        gather_xf(rowBase, w, lm, g, anchor, neighbor, P, idx, xf);

        f32x4 acc[2][8];
#pragma unroll
        for (int i = 0; i < 2; ++i)
#pragma unroll
            for (int c = 0; c < 8; ++c) acc[i][c] = zero;
#pragma unroll
        for (int kc = 0; kc < 3; ++kc) {
            int koff = kc * 32 + g * 8;
#pragma unroll
            for (int ct = 0; ct < 8; ++ct) {
                bf16x8 wf = *(const bf16x8*)&W0p[(ct * 16 + lm) * K0P + koff];
                acc[0][ct] = __builtin_amdgcn_mfma_f32_16x16x32_bf16(xf[0][kc], wf, acc[0][ct], 0, 0, 0);
                acc[1][ct] = __builtin_amdgcn_mfma_f32_16x16x32_bf16(xf[1][kc], wf, acc[1][ct], 0, 0, 0);
            }
        }
#pragma unroll
        for (int ct = 0; ct < 8; ++ct) {
            int c_ = lm + 16 * ct;
            float psum = 0.f, psq = 0.f;
#pragma unroll
            for (int i = 0; i < 2; ++i)
#pragma unroll
                for (int rg = 0; rg < 4; ++rg) {
                    int r_ = w * 32 + i * 16 + g * 4 + rg;
                    float v = fmaxf(acc[i][ct][rg], 0.0f);
                    *(short*)((char*)&Y[tt][0] + yoff(r_, c_ * 2)) = (short)f2bf(v);
                    psum += v; psq += v * v;
                }
            psum += __shfl_xor(psum, 16); psq += __shfl_xor(psq, 16);
            psum += __shfl_xor(psum, 32); psq += __shfl_xor(psq, 32);
            if (lane < 16) {
                atomicAdd(&sred[c_ * 2 + 0], psum);
                atomicAdd(&sred[c_ * 2 + 1], psq);
            }
        }
    }
    __syncthreads();
    atomicAdd(&stats0[slot * CO * 2 + t], sred[t]);

    gg.sync();   // ---- stats0 complete ----

    // ================= Fold (blocks 0..15): W1s = bf16(W1*sc0), bias1 = sh0 . W1 =================
    if (blockIdx.x < 16) {
        if (t < 128) {
            float S = 0.0f, Q = 0.0f;
#pragma unroll
            for (int s = 0; s < NSLOT; ++s) {
                S += stats0[s * CO * 2 + t * 2 + 0];
                Q += stats0[s * CO * 2 + t * 2 + 1];
            }
            float inv = 1.0f / (float)ROWS;
            float mean = S * inv;
            float var = Q * inv - mean * mean;
            float sc = gamma0[t] * rsqrtf(var + 1e-5f);
            ssc[t] = sc;
            ssh[t] = beta0[t] - mean * sc;
        }
        __syncthreads();
        int r0 = blockIdx.x * 8;
#pragma unroll
        for (int i = 0; i < 4; ++i) {
            int e = (r0 * 128) + i * 256 + t;
            int k = e & 127;
            W1s[e] = (short)f2bf(W1[e] * ssc[k]);
        }
        if (t < 8) {
            const float* wrow = W1 + (r0 + t) * 128;
            float s = 0.0f;
#pragma unroll
            for (int k = 0; k < 128; ++k) s = fmaf(ssh[k], wrow[k], s);
            bias1[r0 + t] = s;
        }
    }

    gg.sync();   // ---- W1s, bias1 ready ----

    // ================= Phase 1: G1 all tiles (A from Y, W1s global-L1) -> raw h1 in Y + stats1 ========
    sred[t] = 0.0f;
    __syncthreads();
    for (int tt = 0; tt < 4; ++tt) {
        bf16x8 a1[2][4];
#pragma unroll
        for (int i = 0; i < 2; ++i) {
            int r_ = w * 32 + i * 16 + lm;
#pragma unroll
            for (int kc = 0; kc < 4; ++kc)
                a1[i][kc] = *(const bf16x8*)((const char*)&Y[tt][0] + yoff(r_, kc * 64 + g * 16));
        }
        f32x4 acc[2][8];
#pragma unroll
        for (int ct = 0; ct < 8; ++ct) {
            float b = bias1[lm + 16 * ct];
            f32x4 binit = {b, b, b, b};
            acc[0][ct] = binit;
            acc[1][ct] = binit;
        }
#pragma unroll
        for (int kc = 0; kc < 4; ++kc) {
            int k0 = kc * 32 + g * 8;
#pragma unroll
            for (int ct = 0; ct < 8; ++ct) {
                bf16x8 bfr = *(const bf16x8*)&W1s[(ct * 16 + lm) * CO + k0];
                acc[0][ct] = __builtin_amdgcn_mfma_f32_16x16x32_bf16(a1[0][kc], bfr, acc[0][ct], 0, 0, 0);
                acc[1][ct] = __builtin_amdgcn_mfma_f32_16x16x32_bf16(a1[1][kc], bfr, acc[1][ct], 0, 0, 0);
            }
        }
#pragma unroll
        for (int ct = 0; ct < 8; ++ct) {
            int c_ = lm + 16 * ct;
            float psum = 0.f, psq = 0.f;
#pragma unroll
            for (int i = 0; i < 2; ++i)
#pragma unroll
                for (int rg = 0; rg < 4; ++rg) {
                    int r_ = w * 32 + i * 16 + g * 4 + rg;
                    float v = acc[i][ct][rg];
                    *(short*)((char*)&Y[tt][0] + yoff(r_, c_ * 2)) = (short)f2bf(v);
                    psum += v; psq += v * v;
                }
            psum += __shfl_xor(psum, 16); psq += __shfl_xor(psq, 16);
            psum += __shfl_xor(psum, 32); psq += __shfl_xor(psq, 32);
            if (lane < 16) {
                atomicAdd(&sred[c_ * 2 + 0], psum);
                atomicAdd(&sred[c_ * 2 + 1], psq);
            }
        }
    }
    __syncthreads();
    atomicAdd(&stats1[slot * CO * 2 + t], sred[t]);

    gg.sync();   // ---- stats1 complete ----

    // ================= Phase 2: G2 all tiles (A = relu(BN1(h1)) from Y, W2p global-L1) ==============
    if (t < 128) {
        float S = 0.0f, Q = 0.0f;
#pragma unroll
        for (int s = 0; s < NSLOT; ++s) {
            S += stats1[s * CO * 2 + t * 2 + 0];
            Q += stats1[s * CO * 2 + t * 2 + 1];
        }
        float inv = 1.0f / (float)ROWS;
        float mean = S * inv;
        float var = Q * inv - mean * mean;
        float sc = gamma1[t] * rsqrtf(var + 1e-5f);
        ssc[t] = sc;
        ssh[t] = beta1[t] - mean * sc;
    }
    sred[t] = 0.0f;
    __syncthreads();
    for (int tt = 0; tt < 4; ++tt) {
        int rowBase = blockRow + tt * 128;
        bf16x8 a2[2][4];
#pragma unroll
        for (int kc = 0; kc < 4; ++kc) {
            int k0 = kc * 32 + g * 8;
            float scv[8], shv[8];
#pragma unroll
            for (int j = 0; j < 8; ++j) { scv[j] = ssc[k0 + j]; shv[j] = ssh[k0 + j]; }
#pragma unroll
            for (int i = 0; i < 2; ++i) {
                int r_ = w * 32 + i * 16 + lm;
                bf16x8 raw = *(const bf16x8*)((const char*)&Y[tt][0] + yoff(r_, kc * 64 + g * 16));
#pragma unroll
                for (int j = 0; j < 8; ++j) {
                    float v = fmaxf(bf2f((unsigned short)raw[j]) * scv[j] + shv[j], 0.0f);
                    a2[i][kc][j] = (short)f2bf(v);
                }
            }
        }
        f32x4 acc[2][8];
#pragma unroll
        for (int i = 0; i < 2; ++i)
#pragma unroll
            for (int c = 0; c < 8; ++c) acc[i][c] = zero;
#pragma unroll
        for (int kc = 0; kc < 4; ++kc) {
            int k0 = kc * 32 + g * 8;
#pragma unroll
            for (int ct = 0; ct < 8; ++ct) {
                bf16x8 bfr = *(const bf16x8*)&W2p[(ct * 16 + lm) * CO + k0];
                acc[0][ct] = __builtin_amdgcn_mfma_f32_16x16x32_bf16(a2[0][kc], bfr, acc[0][ct], 0, 0, 0);
                acc[1][ct] = __builtin_amdgcn_mfma_f32_16x16x32_bf16(a2[1][kc], bfr, acc[1][ct], 0, 0, 0);
            }
        }
#pragma unroll
        for (int ct = 0; ct < 8; ++ct) {
            int o = lm + 16 * ct;
            float psum = 0.f, psq = 0.f;
#pragma unroll
            for (int i = 0; i < 2; ++i) {
                float mx = acc[i][ct][0], mn = acc[i][ct][0];
#pragma unroll
                for (int rg = 0; rg < 4; ++rg) {
                    float v = acc[i][ct][rg];
                    psum += v; psq += v * v;
                    mx = fmaxf(mx, v); mn = fminf(mn, v);
                }
                mx = fmaxf(mx, __shfl_xor(mx, 16)); mn = fminf(mn, __shfl_xor(mn, 16));
                mx = fmaxf(mx, __shfl_xor(mx, 32)); mn = fminf(mn, __shfl_xor(mn, 32));
                if (g == 0) {
                    int pt = (rowBase >> 4) + w * 2 + i;   // 0..8191
                    maxh[(size_t)pt * CO + o] = mx;
                    minh[(size_t)pt * CO + o] = mn;
                }
            }
            psum += __shfl_xor(psum, 16); psq += __shfl_xor(psq, 16);
            psum += __shfl_xor(psum, 32); psq += __shfl_xor(psq, 32);
            if (lane < 16) {
                atomicAdd(&sred[o * 2 + 0], psum);
                atomicAdd(&sred[o * 2 + 1], psq);
            }
        }
    }
    __syncthreads();
    atomicAdd(&stats2[slot * CO * 2 + t], sred[t]);
}

// ======================= FALLBACK kernels (r10-verified chain) =======================
__global__ __launch_bounds__(256) void k_g0(const float* __restrict__ anchor,
                                            const float* __restrict__ neighbor,
                                            const unsigned short* __restrict__ P,
                                            const int* __restrict__ idx,
                                            const short* __restrict__ W0p,
                                            unsigned short* __restrict__ y0,
                                            float* __restrict__ stats) {
    __shared__ float sred[CO * 2];
    int t = threadIdx.x;
    int rowBase = blockIdx.x * 128;
    sred[t] = 0.0f;
    __syncthreads();

    int lane = t & 63, w = t >> 6;
    int lm = lane & 15, g = lane >> 4;

    bf16x8 xf[2][3];
    gather_xf(rowBase, w, lm, g, anchor, neighbor, P, idx, xf);

    f32x4 zero = {0.f, 0.f, 0.f, 0.f};
    f32x4 acc[2][8];
#pragma unroll
    for (int i = 0; i < 2; ++i)
#pragma unroll
        for (int c = 0; c < 8; ++c) acc[i][c] = zero;
#pragma unroll
    for (int kc = 0; kc < 3; ++kc) {
        int koff = kc * 32 + g * 8;
#pragma unroll
        for (int ct = 0; ct < 8; ++ct) {
            bf16x8 wf = *(const bf16x8*)&W0p[(ct * 16 + lm) * K0P + koff];
            acc[0][ct] = __builtin_amdgcn_mfma_f32_16x16x32_bf16(xf[0][kc], wf, acc[0][ct], 0, 0, 0);
            acc[1][ct] = __builtin_amdgcn_mfma_f32_16x16x32_bf16(xf[1][kc], wf, acc[1][ct], 0, 0, 0);
        }
    }
#pragma unroll
    for (int ct = 0; ct < 8; ++ct) {
        int o = lm + 16 * ct;
        float psum = 0.f, psq = 0.f;
#pragma unroll
        for (int i = 0; i < 2; ++i)
#pragma unroll
            for (int rg = 0; rg < 4; ++rg) {
                float v = fmaxf(acc[i][ct][rg], 0.0f);
                int r = rowBase + w * 32 + i * 16 + g * 4 + rg;
                y0[(size_t)r * CO + o] = f2bf(v);
                psum += v; psq += v * v;
            }
        psum += __shfl_xor(psum, 16); psq += __shfl_xor(psq, 16);
        psum += __shfl_xor(psum, 32); psq += __shfl_xor(psq, 32);
        if (lane < 16) {
            atomicAdd(&sred[o * 2 + 0], psum);
            atomicAdd(&sred[o * 2 + 1], psq);
        }
    }
    __syncthreads();
    int slot = blockIdx.x & (NSLOT - 1);
    atomicAdd(&stats[slot * CO * 2 + t], sred[t]);
}

__global__ __launch_bounds__(256) void kf_g1(const unsigned short* __restrict__ Xin,
                                             const float* __restrict__ W1,
                                             const float* __restrict__ stats0,
                                             const float* __restrict__ gamma,
                                             const float* __restrict__ beta,
                                             unsigned short* __restrict__ Hout,
                                             float* __restrict__ statsOut) {
    __shared__ alignas(16) short Wl[128 * WST];
    __shared__ float ssc[CO];
    __shared__ float ssh[CO];
    __shared__ float sbias[CO];
    __shared__ float sred[CO * 2];
    int t = threadIdx.x;
    int rowBase = blockIdx.x * 128;
    int lane = t & 63, w = t >> 6;
    int lm = lane & 15, g = lane >> 4;

    bf16x8 afr[2][4];
#pragma unroll
    for (int i = 0; i < 2; ++i) {
        const unsigned short* xr = Xin + (size_t)(rowBase + w * 32 + i * 16 + lm) * CO;
#pragma unroll
        for (int kc = 0; kc < 4; ++kc)
            afr[i][kc] = *(const bf16x8*)(xr + kc * 32 + g * 8);
    }

    sred[t] = 0.0f;
    if (t < 128) {
        float S = 0.0f, Q = 0.0f;
#pragma unroll
        for (int s = 0; s < NSLOT; ++s) {
            S += stats0[s * CO * 2 + t * 2 + 0];
            Q += stats0[s * CO * 2 + t * 2 + 1];
        }
        float inv = 1.0f / (float)ROWS;
        float mean = S * inv;
        float var = Q * inv - mean * mean;
        float sc = gamma[t] * rsqrtf(var + 1e-5f);
        ssc[t] = sc;
        ssh[t] = beta[t] - mean * sc;
    }
    __syncthreads();

#pragma unroll
    for (int q = 0; q < 16; ++q) {
        int e4 = q * 256 + t;
        int o = e4 >> 5, kq = e4 & 31;
        float4 v = ((const float4*)W1)[e4];
        int k = kq * 4;
        ushort4 r;
        r.x = f2bf(v.x * ssc[k + 0]);
        r.y = f2bf(v.y * ssc[k + 1]);
        r.z = f2bf(v.z * ssc[k + 2]);
        r.w = f2bf(v.w * ssc[k + 3]);
        *(ushort4*)&Wl[o * WST + k] = r;
    }
    if (t < 128) {
        const float* wrow = W1 + t * 128;
        float s = 0.0f;
#pragma unroll
        for (int k = 0; k < 128; ++k) s = fmaf(ssh[k], wrow[k], s);
        sbias[t] = s;
    }
    __syncthreads();

    f32x4 acc[2][8];
#pragma unroll
    for (int ct = 0; ct < 8; ++ct) {
        float b = sbias[lm + 16 * ct];
        f32x4 binit = {b, b, b, b};
        acc[0][ct] = binit;
        acc[1][ct] = binit;
    }
#pragma unroll
    for (int kc = 0; kc < 4; ++kc) {
        int k0 = kc * 32 + g * 8;
#pragma unroll
        for (int ct = 0; ct < 8; ++ct) {
            bf16x8 bfr = *(const bf16x8*)&Wl[(ct * 16 + lm) * WST + k0];
            acc[0][ct] = __builtin_amdgcn_mfma_f32_16x16x32_bf16(afr[0][kc], bfr, acc[0][ct], 0, 0, 0);
            acc[1][ct] = __builtin_amdgcn_mfma_f32_16x16x32_bf16(afr[1][kc], bfr, acc[1][ct], 0, 0, 0);
        }
    }

#pragma unroll
    for (int ct = 0; ct < 8; ++ct) {
        int o = lm + 16 * ct;
        float psum = 0.f, psq = 0.f;
#pragma unroll
        for (int i = 0; i < 2; ++i)
#pragma unroll
            for (int rg = 0; rg < 4; ++rg) {
                float v = acc[i][ct][rg];
                int r = rowBase + w * 32 + i * 16 + g * 4 + rg;
                Hout[(size_t)r * CO + o] = f2bf(v);
                psum += v; psq += v * v;
            }
        psum += __shfl_xor(psum, 16); psq += __shfl_xor(psq, 16);
        psum += __shfl_xor(psum, 32); psq += __shfl_xor(psq, 32);
        if (lane < 16) {
            atomicAdd(&sred[o * 2 + 0], psum);
            atomicAdd(&sred[o * 2 + 1], psq);
        }
    }
    __syncthreads();
    int slot = blockIdx.x & (NSLOT - 1);
    atomicAdd(&statsOut[slot * CO * 2 + t], sred[t]);
}

__global__ __launch_bounds__(256) void kf_g2(const unsigned short* __restrict__ Xin,
                                             const short* __restrict__ Wp,
                                             const float* __restrict__ statsIn,
                                             const float* __restrict__ gamma,
                                             const float* __restrict__ beta,
                                             float* __restrict__ maxh,
                                             float* __restrict__ minh,
                                             float* __restrict__ statsOut) {
    __shared__ alignas(16) short Wl[128 * WST];
    __shared__ float ssc[CO];
    __shared__ float ssh[CO];
    __shared__ float sred[CO * 2];
    int t = threadIdx.x;
    int rowBase = blockIdx.x * 128;
    int lane = t & 63, w = t >> 6;
    int lm = lane & 15, g = lane >> 4;

    uint4 xraw[2][4];
#pragma unroll
    for (int i = 0; i < 2; ++i) {
        const unsigned short* xr = Xin + (size_t)(rowBase + w * 32 + i * 16 + lm) * CO;
#pragma unroll
        for (int kc = 0; kc < 4; ++kc)
            xraw[i][kc] = *(const uint4*)(xr + kc * 32 + g * 8);
    }

    sred[t] = 0.0f;
    if (t < 128) {
        float S = 0.0f, Q = 0.0f;
#pragma unroll
        for (int s = 0; s < NSLOT; ++s) {
            S += statsIn[s * CO * 2 + t * 2 + 0];
            Q += statsIn[s * CO * 2 + t * 2 + 1];
        }
        float inv = 1.0f / (float)ROWS;
        float mean = S * inv;
        float var = Q * inv - mean * mean;
        float sc = gamma[t] * rsqrtf(var + 1e-5f);
        ssc[t] = sc;
        ssh[t] = beta[t] - mean * sc;
    }

#pragma unroll
    for (int q = 0; q < 8; ++q) {
        int e = (q * 256 + t) * 8;
        int o = e >> 7, k = e & 127;
        *(uint4*)&Wl[o * WST + k] = *(const uint4*)&Wp[e];
    }
    __syncthreads();

    f32x4 zero = {0.f, 0.f, 0.f, 0.f};
    f32x4 acc[2][8];
#pragma unroll
    for (int i = 0; i < 2; ++i)
#pragma unroll
        for (int c = 0; c < 8; ++c) acc[i][c] = zero;

#pragma unroll
    for (int kc = 0; kc < 4; ++kc) {
        int k0 = kc * 32 + g * 8;
        float scv[8], shv[8];
#pragma unroll
        for (int j = 0; j < 8; ++j) { scv[j] = ssc[k0 + j]; shv[j] = ssh[k0 + j]; }

        bf16x8 afr[2];
#pragma unroll
        for (int i = 0; i < 2; ++i) {
            U16B u; u.v = xraw[i][kc];
#pragma unroll
            for (int j = 0; j < 8; ++j) {
                float v = fmaxf(bf2f(u.us[j]) * scv[j] + shv[j], 0.0f);
                afr[i][j] = (short)f2bf(v);
            }
        }
#pragma unroll
        for (int ct = 0; ct < 8; ++ct) {
            bf16x8 bfr = *(const bf16x8*)&Wl[(ct * 16 + lm) * WST + k0];
            acc[0][ct] = __builtin_amdgcn_mfma_f32_16x16x32_bf16(afr[0], bfr, acc[0][ct], 0, 0, 0);
            acc[1][ct] = __builtin_amdgcn_mfma_f32_16x16x32_bf16(afr[1], bfr, acc[1][ct], 0, 0, 0);
        }
    }

#pragma unroll
    for (int ct = 0; ct < 8; ++ct) {
        int o = lm + 16 * ct;
        float psum = 0.f, psq = 0.f;
#pragma unroll
        for (int i = 0; i < 2; ++i) {
            float mx = acc[i][ct][0], mn = acc[i][ct][0];
#pragma unroll
            for (int rg = 0; rg < 4; ++rg) {
                float v = acc[i][ct][rg];
                psum += v; psq += v * v;
                mx = fmaxf(mx, v); mn = fminf(mn, v);
            }
            mx = fmaxf(mx, __shfl_xor(mx, 16)); mn = fminf(mn, __shfl_xor(mn, 16));
            mx = fmaxf(mx, __shfl_xor(mx, 32)); mn = fminf(mn, __shfl_xor(mn, 32));
            if (g == 0) {
                int pt = (rowBase >> 4) + w * 2 + i;
                maxh[(size_t)pt * CO + o] = mx;
                minh[(size_t)pt * CO + o] = mn;
            }
        }
        psum += __shfl_xor(psum, 16); psq += __shfl_xor(psq, 16);
        psum += __shfl_xor(psum, 32); psq += __shfl_xor(psq, 32);
        if (lane < 16) {
            atomicAdd(&sred[o * 2 + 0], psum);
            atomicAdd(&sred[o * 2 + 1], psq);
        }
    }
    __syncthreads();
    int slot = blockIdx.x & (NSLOT - 1);
    atomicAdd(&statsOut[slot * CO * 2 + t], sred[t]);
}

// ---------------- output: BN2-finalize + monotone-select ----------------
__global__ __launch_bounds__(256) void k_out(const float* __restrict__ maxh,
                                             const float* __restrict__ minh,
                                             const float* __restrict__ statsIn,
                                             const float* __restrict__ gamma,
                                             const float* __restrict__ beta,
                                             float* __restrict__ out) {
    __shared__ float ssc[CO];
    __shared__ float ssh[CO];
    int t = threadIdx.x;
    if (t < 128) {
        float S = 0.0f, Q = 0.0f;
#pragma unroll
        for (int s = 0; s < NSLOT; ++s) {
            S += statsIn[s * CO * 2 + t * 2 + 0];
            Q += statsIn[s * CO * 2 + t * 2 + 1];
        }
        float inv = 1.0f / (float)ROWS;
        float mean = S * inv;
        float var = Q * inv - mean * mean;
        float sc = gamma[t] * rsqrtf(var + 1e-5f);
        ssc[t] = sc;
        ssh[t] = beta[t] - mean * sc;
    }
    __syncthreads();

    int i4 = blockIdx.x * 256 + t;
    float4 mx = ((const float4*)maxh)[i4];
    float4 mn = ((const float4*)minh)[i4];
    int o = (i4 * 4) & 127;
    float4 r;
    {
        float sc = ssc[o + 0], sh = ssh[o + 0];
        r.x = fmaxf(sc * (sc >= 0.f ? mx.x : mn.x) + sh, 0.f);
        sc = ssc[o + 1]; sh = ssh[o + 1];
        r.y = fmaxf(sc * (sc >= 0.f ? mx.y : mn.y) + sh, 0.f);
        sc = ssc[o + 2]; sh = ssh[o + 2];
        r.z = fmaxf(sc * (sc >= 0.f ? mx.z : mn.z) + sh, 0.f);
        sc = ssc[o + 3]; sh = ssh[o + 3];
        r.w = fmaxf(sc * (sc >= 0.f ? mx.w : mn.w) + sh, 0.f);
    }
    ((float4*)out)[i4] = r;
}

extern "C" void kernel_launch(void* const* d_in, const int* in_sizes, int n_in,
                              void* d_out, int out_size, void* d_ws, size_t ws_size,
                              hipStream_t stream) {
    (void)in_sizes; (void)n_in; (void)out_size; (void)ws_size;
    const float* anchor = (const float*)d_in[0];
    const float* neighbor = (const float*)d_in[1];
    const float* nfeat = (const float*)d_in[2];
    const float* feat = (const float*)d_in[3];
    const float* W0 = (const float*)d_in[4];
    const float* g0 = (const float*)d_in[5];
    const float* b0 = (const float*)d_in[6];
    const float* W1 = (const float*)d_in[7];
    const float* g1 = (const float*)d_in[8];
    const float* b1 = (const float*)d_in[9];
    const float* W2 = (const float*)d_in[10];
    const float* g2 = (const float*)d_in[11];
    const float* b2 = (const float*)d_in[12];
    float* out = (float*)d_out;

    char* ws = (char*)d_ws;
    size_t o_idx = 0;                                   // 512 KB
    size_t o_P = o_idx + (size_t)ROWS * 4;              // bf16 P: 1 MB
    size_t o_stats = o_P + (size_t)BB * NN * CC * 2;    // 48 KB
    size_t o_W0p = o_stats + 3 * NSLOT * CO * 2 * 4;    // 24576 B
    size_t o_W2p = o_W0p + 128 * K0P * 2;               // 32768 B
    size_t o_W1s = o_W2p + 16384 * 2;                   // 32768 B
    size_t o_bias = o_W1s + 16384 * 2;                  // 512 B
    size_t o_maxh = (o_bias + 512 + 255) & ~(size_t)255;
    size_t o_minh = o_maxh + (size_t)BB * NN * CO * 4;  // 4 MB each
    size_t o_y0 = o_minh + (size_t)BB * NN * CO * 4;    // bf16: 32 MB (fallback)
    size_t o_h1 = o_y0 + (size_t)ROWS * CO * 2;         // bf16: 32 MB (fallback)

    int* idx = (int*)(ws + o_idx);
    unsigned short* P = (unsigned short*)(ws + o_P);
    float* stats0 = (float*)(ws + o_stats);
    float* stats1 = stats0 + NSLOT * CO * 2;
    float* stats2 = stats1 + NSLOT * CO * 2;
    short* W0p = (short*)(ws + o_W0p);
    short* W2p = (short*)(ws + o_W2p);
    short* W1s = (short*)(ws + o_W1s);
    float* bias1 = (float*)(ws + o_bias);
    float* maxh = (float*)(ws + o_maxh);
    float* minh = (float*)(ws + o_minh);
    unsigned short* y0 = (unsigned short*)(ws + o_y0);
    unsigned short* h1 = (unsigned short*)(ws + o_h1);

    k_pre<<<PRE_PREP + PRE_PROD + PRE_BALL, 256, 0, stream>>>(
        anchor, neighbor, feat, nfeat, W0, W2, W0p, W2p, stats0, idx, P);

    void* margs[] = {
        (void*)&anchor, (void*)&neighbor, (void*)&P, (void*)&idx,
        (void*)&W0p, (void*)&W1, (void*)&W2p,
        (void*)&g0, (void*)&b0, (void*)&g1, (void*)&b1,
        (void*)&W1s, (void*)&bias1,
        (void*)&stats0, (void*)&stats1, (void*)&stats2,
        (void*)&maxh, (void*)&minh};
    hipError_t cer = hipLaunchCooperativeKernel((void*)k_mega, dim3(256), dim3(256),
                                                margs, 0, stream);
    if (cer != hipSuccess) {
        (void)hipGetLastError();   // clear sticky error; use verified multi-kernel path
        k_g0<<<ROWS / 128, 256, 0, stream>>>(anchor, neighbor, P, idx, W0p, y0, stats0);
        kf_g1<<<ROWS / 128, 256, 0, stream>>>(y0, W1, stats0, g0, b0, h1, stats1);
        kf_g2<<<ROWS / 128, 256, 0, stream>>>(h1, W2p, stats1, g1, b1, maxh, minh, stats2);
    }

    k_out<<<BB * NN * CO / 1024, 256, 0, stream>>>(maxh, minh, stats2, g2, b2, out);
}

// Round 16
// 102.637 us; speedup vs baseline: 1.7579x; 1.7579x over previous
//
#include <hip/hip_runtime.h>
#include <hip/hip_bf16.h>

#define BB 2
#define NN 4096
#define KNN 16
#define CC 64
#define CO 128
#define ROWS (BB*NN*KNN)   // 131072
#define K0P 96             // padded/permuted K for layer 0
#define NSLOT 16
#define WST 136            // 128 + 8 pad (bf16 elems)

// k_pre block ranges
#define PRE_PREP 112       // covers i < 28672
#define PRE_PROD 512       // 131072 float4 elems
#define PRE_BALL 2048      // 8192 anchors / 4 per block

typedef __attribute__((ext_vector_type(8))) short bf16x8;
typedef __attribute__((ext_vector_type(4))) float f32x4;

__device__ __forceinline__ float bf2f(unsigned short u) {
    return __uint_as_float(((unsigned)u) << 16);
}
__device__ __forceinline__ unsigned short f2bf(float f) {
    __hip_bfloat16 h = __float2bfloat16(f);
    return *reinterpret_cast<unsigned short*>(&h);
}

union U16B { uint4 v; unsigned short us[8]; };

// ======================= k_pre: stats-zero + W0 permute/cvt + W2 cvt + prod + ball =======================
__global__ __launch_bounds__(256) void k_pre(const float* __restrict__ anchor,
                                             const float* __restrict__ neighbor,
                                             const float* __restrict__ feat,
                                             const float* __restrict__ nfeat,
                                             const float* __restrict__ W0,
                                             const float* __restrict__ W2,
                                             short* __restrict__ W0p,
                                             short* __restrict__ W2p,
                                             float* __restrict__ stats,
                                             int* __restrict__ idx,
                                             unsigned short* __restrict__ P) {
    int blk = blockIdx.x;
    int t = threadIdx.x;
    if (blk < PRE_PREP) {
        int i = blk * 256 + t;
        if (i < 3 * NSLOT * CO * 2) stats[i] = 0.0f;          // 12288 floats
        if (i < 128 * K0P) {                                   // 12288
            int o = i / K0P, k = i - o * K0P;
            float v;
            if (k < 64)      v = W0[o * 67 + 3 + k];
            else if (k < 67) v = W0[o * 67 + (k - 64)];
            else             v = 0.0f;
            W0p[i] = (short)f2bf(v);
        } else if (i < 128 * K0P + 16384) {
            int e = i - 128 * K0P;
            W2p[e] = (short)f2bf(W2[e]);
        }
    } else if (blk < PRE_PREP + PRE_PROD) {
        int i = (blk - PRE_PREP) * 256 + t;                    // < 131072
        float4 a = ((const float4*)feat)[i];
        float4 b = ((const float4*)nfeat)[i];
        ushort4 r;
        r.x = f2bf(__fmul_rn(a.x, b.x));
        r.y = f2bf(__fmul_rn(a.y, b.y));
        r.z = f2bf(__fmul_rn(a.z, b.z));
        r.w = f2bf(__fmul_rn(a.w, b.w));
        ((ushort4*)P)[i] = r;
    } else {
        // ball query: one anchor per wave, ballot ordered extraction
        int lane = t & 63;
        int an = (blk - PRE_PREP - PRE_PROD) * 4 + (t >> 6);   // 0..8191
        int b = an >> 12;
        const float* nb = neighbor + (size_t)b * NN * 3;

        float ax = anchor[an * 3 + 0];
        float ay = anchor[an * 3 + 1];
        float az = anchor[an * 3 + 2];

        unsigned long long lmask = (lane == 63) ? 0xFFFFFFFFFFFFFFFFull >> 1
                                                : ((1ull << lane) - 1ull);
        int cnt = 0;
        int firstIdx = -1;
        int* myout = idx + (size_t)an * KNN;

        for (int chunk = 0; chunk < NN / 64 && cnt < KNN; ++chunk) {
            int j = chunk * 64 + lane;
            float dx = __fsub_rn(ax, nb[j * 3 + 0]);
            float dy = __fsub_rn(ay, nb[j * 3 + 1]);
            float dz = __fsub_rn(az, nb[j * 3 + 2]);
            float d2 = __fadd_rn(__fadd_rn(__fmul_rn(dx, dx), __fmul_rn(dy, dy)),
                                 __fmul_rn(dz, dz));
            bool hit = d2 < 1.0f;
            unsigned long long m = __ballot(hit);
            if (m) {
                int pos = cnt + __popcll(m & lmask);
                if (hit && pos < KNN) myout[pos] = j;
                if (firstIdx < 0) firstIdx = chunk * 64 + (__ffsll((long long)m) - 1);
                cnt += __popcll(m);
            }
        }
        if (cnt < KNN) {
            int f = (firstIdx < 0) ? 0 : firstIdx;
            if (lane >= cnt && lane < KNN) myout[lane] = f;
        }
    }
}

// gather X fragments for GEMM0 (xf[2][3])
__device__ __forceinline__ void gather_xf(int rowBase, int w, int lm, int g,
                                          const float* anchor, const float* neighbor,
                                          const unsigned short* P, const int* idx,
                                          bf16x8 xf[2][3]) {
#pragma unroll
    for (int i = 0; i < 2; ++i) {
        int r = rowBase + w * 32 + i * 16 + lm;
        int bn = r >> 4;
        int bb = r >> 16;
        int j = idx[r];
        const unsigned short* Prow = P + ((size_t)(bb << 12) + j) * CC;
        xf[i][0] = *(const bf16x8*)(Prow + g * 8);
        xf[i][1] = *(const bf16x8*)(Prow + 32 + g * 8);
        bf16x8 x2 = {0, 0, 0, 0, 0, 0, 0, 0};
        if (g == 0) {
            const float* nbr = neighbor + ((size_t)(bb << 12) + j) * 3;
            float dx = __fsub_rn(anchor[bn * 3 + 0], nbr[0]);
            float dy = __fsub_rn(anchor[bn * 3 + 1], nbr[1]);
            float dz = __fsub_rn(anchor[bn * 3 + 2], nbr[2]);
            x2[0] = (short)f2bf(dx);
            x2[1] = (short)f2bf(dy);
            x2[2] = (short)f2bf(dz);
        }
        xf[i][2] = x2;
    }
}

// ======================= k_g0: gather + GEMM0 (LDS-free W0p) -> y0 + stats0 =======================
__global__ __launch_bounds__(256) void k_g0(const float* __restrict__ anchor,
                                            const float* __restrict__ neighbor,
                                            const unsigned short* __restrict__ P,
                                            const int* __restrict__ idx,
                                            const short* __restrict__ W0p,
                                            unsigned short* __restrict__ y0,
                                            float* __restrict__ stats) {
    __shared__ float sred[CO * 2];
    int t = threadIdx.x;
    int rowBase = blockIdx.x * 128;
    sred[t] = 0.0f;
    __syncthreads();

    int lane = t & 63, w = t >> 6;
    int lm = lane & 15, g = lane >> 4;

    bf16x8 xf[2][3];
    gather_xf(rowBase, w, lm, g, anchor, neighbor, P, idx, xf);

    f32x4 zero = {0.f, 0.f, 0.f, 0.f};
    f32x4 acc[2][8];
#pragma unroll
    for (int i = 0; i < 2; ++i)
#pragma unroll
        for (int c = 0; c < 8; ++c) acc[i][c] = zero;

#pragma unroll
    for (int kc = 0; kc < 3; ++kc) {
        int koff = kc * 32 + g * 8;
#pragma unroll
        for (int ct = 0; ct < 8; ++ct) {
            bf16x8 wf = *(const bf16x8*)&W0p[(ct * 16 + lm) * K0P + koff];
            acc[0][ct] = __builtin_amdgcn_mfma_f32_16x16x32_bf16(xf[0][kc], wf, acc[0][ct], 0, 0, 0);
            acc[1][ct] = __builtin_amdgcn_mfma_f32_16x16x32_bf16(xf[1][kc], wf, acc[1][ct], 0, 0, 0);
        }
    }

#pragma unroll
    for (int ct = 0; ct < 8; ++ct) {
        int o = lm + 16 * ct;
        float psum = 0.f, psq = 0.f;
#pragma unroll
        for (int i = 0; i < 2; ++i)
#pragma unroll
            for (int rg = 0; rg < 4; ++rg) {
                float v = fmaxf(acc[i][ct][rg], 0.0f);
                int r = rowBase + w * 32 + i * 16 + g * 4 + rg;
                y0[(size_t)r * CO + o] = f2bf(v);
                psum += v; psq += v * v;
            }
        psum += __shfl_xor(psum, 16); psq += __shfl_xor(psq, 16);
        psum += __shfl_xor(psum, 32); psq += __shfl_xor(psq, 32);
        if (lane < 16) {
            atomicAdd(&sred[o * 2 + 0], psum);
            atomicAdd(&sred[o * 2 + 1], psq);
        }
    }
    __syncthreads();
    int slot = blockIdx.x & (NSLOT - 1);
    atomicAdd(&stats[slot * CO * 2 + t], sred[t]);
}

// ======================= k_fold: BN0-finalize -> W1s (bf16, scaled) + bias1 =======================
// 16 blocks x 256 threads; block b handles rows 8b..8b+7.
__global__ __launch_bounds__(256) void k_fold(const float* __restrict__ stats0,
                                              const float* __restrict__ gamma,
                                              const float* __restrict__ beta,
                                              const float* __restrict__ W1,
                                              short* __restrict__ W1s,
                                              float* __restrict__ bias1) {
    __shared__ float ssc[CO];
    __shared__ float ssh[CO];
    int t = threadIdx.x;
    if (t < 128) {
        float S = 0.0f, Q = 0.0f;
#pragma unroll
        for (int s = 0; s < NSLOT; ++s) {
            S += stats0[s * CO * 2 + t * 2 + 0];
            Q += stats0[s * CO * 2 + t * 2 + 1];
        }
        float inv = 1.0f / (float)ROWS;
        float mean = S * inv;
        float var = Q * inv - mean * mean;
        float sc = gamma[t] * rsqrtf(var + 1e-5f);
        ssc[t] = sc;
        ssh[t] = beta[t] - mean * sc;
    }
    __syncthreads();
    int r0 = blockIdx.x * 8;
#pragma unroll
    for (int i = 0; i < 4; ++i) {
        int e = (r0 * 128) + i * 256 + t;     // 1024 elems per block
        int k = e & 127;
        W1s[e] = (short)f2bf(W1[e] * ssc[k]);
    }
    if (t < 8) {
        const float* wrow = W1 + (r0 + t) * 128;
        float s = 0.0f;
#pragma unroll
        for (int k = 0; k < 128; ++k) s = fmaf(ssh[k], wrow[k], s);
        bias1[r0 + t] = s;
    }
}

// ======================= k_g1: y0 @ W1s^T + bias1 -> h1 + stats1 (bf16 W LDS-staged) =======================
__global__ __launch_bounds__(256) void k_g1(const unsigned short* __restrict__ Xin,
                                            const short* __restrict__ W1s,
                                            const float* __restrict__ bias1,
                                            unsigned short* __restrict__ Hout,
                                            float* __restrict__ stats1) {
    __shared__ alignas(16) short Wl[128 * WST];
    __shared__ float sbias[CO];
    __shared__ float sred[CO * 2];
    int t = threadIdx.x;
    int rowBase = blockIdx.x * 128;
    int lane = t & 63, w = t >> 6;
    int lm = lane & 15, g = lane >> 4;

    // prefetch A fragments from y0 (issued before W-stage so HBM latency hides)
    bf16x8 afr[2][4];
#pragma unroll
    for (int i = 0; i < 2; ++i) {
        const unsigned short* xr = Xin + (size_t)(rowBase + w * 32 + i * 16 + lm) * CO;
#pragma unroll
        for (int kc = 0; kc < 4; ++kc)
            afr[i][kc] = *(const bf16x8*)(xr + kc * 32 + g * 8);
    }

    sred[t] = 0.0f;
    if (t < 128) sbias[t] = bias1[t];
    // stage prep'd bf16 W1s -> LDS (coalesced uint4, 8 per thread)
#pragma unroll
    for (int q = 0; q < 8; ++q) {
        int e = (q * 256 + t) * 8;       // element index
        int o = e >> 7, k = e & 127;
        *(uint4*)&Wl[o * WST + k] = *(const uint4*)&W1s[e];
    }
    __syncthreads();

    f32x4 acc[2][8];
#pragma unroll
    for (int ct = 0; ct < 8; ++ct) {
        float b = sbias[lm + 16 * ct];
        f32x4 binit = {b, b, b, b};
        acc[0][ct] = binit;
        acc[1][ct] = binit;
    }
#pragma unroll
    for (int kc = 0; kc < 4; ++kc) {
        int k0 = kc * 32 + g * 8;
#pragma unroll
        for (int ct = 0; ct < 8; ++ct) {
            bf16x8 bfr = *(const bf16x8*)&Wl[(ct * 16 + lm) * WST + k0];
            acc[0][ct] = __builtin_amdgcn_mfma_f32_16x16x32_bf16(afr[0][kc], bfr, acc[0][ct], 0, 0, 0);
            acc[1][ct] = __builtin_amdgcn_mfma_f32_16x16x32_bf16(afr[1][kc], bfr, acc[1][ct], 0, 0, 0);
        }
    }

    // epilogue: store raw h1 bf16 + stats on raw values
#pragma unroll
    for (int ct = 0; ct < 8; ++ct) {
        int o = lm + 16 * ct;
        float psum = 0.f, psq = 0.f;
#pragma unroll
        for (int i = 0; i < 2; ++i)
#pragma unroll
            for (int rg = 0; rg < 4; ++rg) {
                float v = acc[i][ct][rg];
                int r = rowBase + w * 32 + i * 16 + g * 4 + rg;
                Hout[(size_t)r * CO + o] = f2bf(v);
                psum += v; psq += v * v;
            }
        psum += __shfl_xor(psum, 16); psq += __shfl_xor(psq, 16);
        psum += __shfl_xor(psum, 32); psq += __shfl_xor(psq, 32);
        if (lane < 16) {
            atomicAdd(&sred[o * 2 + 0], psum);
            atomicAdd(&sred[o * 2 + 1], psq);
        }
    }
    __syncthreads();
    int slot = blockIdx.x & (NSLOT - 1);
    atomicAdd(&stats1[slot * CO * 2 + t], sred[t]);
}

// ======================= k_g2: relu(BN1(h1)) @ W2p^T -> max/min + stats2 (r10-verified) =======================
__global__ __launch_bounds__(256) void k_g2(const unsigned short* __restrict__ Xin,
                                            const short* __restrict__ Wp,
                                            const float* __restrict__ statsIn,
                                            const float* __restrict__ gamma,
                                            const float* __restrict__ beta,
                                            float* __restrict__ maxh,
                                            float* __restrict__ minh,
                                            float* __restrict__ statsOut) {
    __shared__ alignas(16) short Wl[128 * WST];
    __shared__ float ssc[CO];
    __shared__ float ssh[CO];
    __shared__ float sred[CO * 2];
    int t = threadIdx.x;
    int rowBase = blockIdx.x * 128;
    int lane = t & 63, w = t >> 6;
    int lm = lane & 15, g = lane >> 4;

    // prefetch raw A rows (uint4 bits)
    uint4 xraw[2][4];
#pragma unroll
    for (int i = 0; i < 2; ++i) {
        const unsigned short* xr = Xin + (size_t)(rowBase + w * 32 + i * 16 + lm) * CO;
#pragma unroll
        for (int kc = 0; kc < 4; ++kc)
            xraw[i][kc] = *(const uint4*)(xr + kc * 32 + g * 8);
    }

    sred[t] = 0.0f;
    if (t < 128) {
        float S = 0.0f, Q = 0.0f;
#pragma unroll
        for (int s = 0; s < NSLOT; ++s) {
            S += statsIn[s * CO * 2 + t * 2 + 0];
            Q += statsIn[s * CO * 2 + t * 2 + 1];
        }
        float inv = 1.0f / (float)ROWS;
        float mean = S * inv;
        float var = Q * inv - mean * mean;
        float sc = gamma[t] * rsqrtf(var + 1e-5f);
        ssc[t] = sc;
        ssh[t] = beta[t] - mean * sc;
    }

    // stage W2p -> LDS (coalesced uint4)
#pragma unroll
    for (int q = 0; q < 8; ++q) {
        int e = (q * 256 + t) * 8;
        int o = e >> 7, k = e & 127;
        *(uint4*)&Wl[o * WST + k] = *(const uint4*)&Wp[e];
    }
    __syncthreads();

    f32x4 zero = {0.f, 0.f, 0.f, 0.f};
    f32x4 acc[2][8];
#pragma unroll
    for (int i = 0; i < 2; ++i)
#pragma unroll
        for (int c = 0; c < 8; ++c) acc[i][c] = zero;

#pragma unroll
    for (int kc = 0; kc < 4; ++kc) {
        int k0 = kc * 32 + g * 8;
        float scv[8], shv[8];
#pragma unroll
        for (int j = 0; j < 8; ++j) { scv[j] = ssc[k0 + j]; shv[j] = ssh[k0 + j]; }

        bf16x8 afr[2];
#pragma unroll
        for (int i = 0; i < 2; ++i) {
            U16B u; u.v = xraw[i][kc];
#pragma unroll
            for (int j = 0; j < 8; ++j) {
                float v = fmaxf(bf2f(u.us[j]) * scv[j] + shv[j], 0.0f);
                afr[i][j] = (short)f2bf(v);
            }
        }
#pragma unroll
        for (int ct = 0; ct < 8; ++ct) {
            bf16x8 bfr = *(const bf16x8*)&Wl[(ct * 16 + lm) * WST + k0];
            acc[0][ct] = __builtin_amdgcn_mfma_f32_16x16x32_bf16(afr[0], bfr, acc[0][ct], 0, 0, 0);
            acc[1][ct] = __builtin_amdgcn_mfma_f32_16x16x32_bf16(afr[1], bfr, acc[1][ct], 0, 0, 0);
        }
    }

    // epilogue: per-point K-max/min of raw h2 (f32) + stats2
#pragma unroll
    for (int ct = 0; ct < 8; ++ct) {
        int o = lm + 16 * ct;
        float psum = 0.f, psq = 0.f;
#pragma unroll
        for (int i = 0; i < 2; ++i) {
            float mx = acc[i][ct][0], mn = acc[i][ct][0];
#pragma unroll
            for (int rg = 0; rg < 4; ++rg) {
                float v = acc[i][ct][rg];
                psum += v; psq += v * v;
                mx = fmaxf(mx, v); mn = fminf(mn, v);
            }
            mx = fmaxf(mx, __shfl_xor(mx, 16)); mn = fminf(mn, __shfl_xor(mn, 16));
            mx = fmaxf(mx, __shfl_xor(mx, 32)); mn = fminf(mn, __shfl_xor(mn, 32));
            if (g == 0) {
                int pt = (rowBase >> 4) + w * 2 + i;   // point index 0..8191
                maxh[(size_t)pt * CO + o] = mx;
                minh[(size_t)pt * CO + o] = mn;
            }
        }
        psum += __shfl_xor(psum, 16); psq += __shfl_xor(psq, 16);
        psum += __shfl_xor(psum, 32); psq += __shfl_xor(psq, 32);
        if (lane < 16) {
            atomicAdd(&sred[o * 2 + 0], psum);
            atomicAdd(&sred[o * 2 + 1], psq);
        }
    }
    __syncthreads();
    int slot = blockIdx.x & (NSLOT - 1);
    atomicAdd(&statsOut[slot * CO * 2 + t], sred[t]);
}

// ---------------- output: BN2-finalize + monotone-select; out = relu(sc*(sc>=0?maxh:minh)+sh) ----------------
__global__ __launch_bounds__(256) void k_out(const float* __restrict__ maxh,
                                             const float* __restrict__ minh,
                                             const float* __restrict__ statsIn,
                                             const float* __restrict__ gamma,
                                             const float* __restrict__ beta,
                                             float* __restrict__ out) {
    __shared__ float ssc[CO];
    __shared__ float ssh[CO];
    int t = threadIdx.x;
    if (t < 128) {
        float S = 0.0f, Q = 0.0f;
#pragma unroll
        for (int s = 0; s < NSLOT; ++s) {
            S += statsIn[s * CO * 2 + t * 2 + 0];
            Q += statsIn[s * CO * 2 + t * 2 + 1];
        }
        float inv = 1.0f / (float)ROWS;
        float mean = S * inv;
        float var = Q * inv - mean * mean;
        float sc = gamma[t] * rsqrtf(var + 1e-5f);
        ssc[t] = sc;
        ssh[t] = beta[t] - mean * sc;
    }
    __syncthreads();

    int i4 = blockIdx.x * 256 + t;           // float4 index over 1M elems
    float4 mx = ((const float4*)maxh)[i4];
    float4 mn = ((const float4*)minh)[i4];
    int o = (i4 * 4) & 127;
    float4 r;
    {
        float sc = ssc[o + 0], sh = ssh[o + 0];
        r.x = fmaxf(sc * (sc >= 0.f ? mx.x : mn.x) + sh, 0.f);
        sc = ssc[o + 1]; sh = ssh[o + 1];
        r.y = fmaxf(sc * (sc >= 0.f ? mx.y : mn.y) + sh, 0.f);
        sc = ssc[o + 2]; sh = ssh[o + 2];
        r.z = fmaxf(sc * (sc >= 0.f ? mx.z : mn.z) + sh, 0.f);
        sc = ssc[o + 3]; sh = ssh[o + 3];
        r.w = fmaxf(sc * (sc >= 0.f ? mx.w : mn.w) + sh, 0.f);
    }
    ((float4*)out)[i4] = r;
}

extern "C" void kernel_launch(void* const* d_in, const int* in_sizes, int n_in,
                              void* d_out, int out_size, void* d_ws, size_t ws_size,
                              hipStream_t stream) {
    (void)in_sizes; (void)n_in; (void)out_size; (void)ws_size;
    const float* anchor = (const float*)d_in[0];
    const float* neighbor = (const float*)d_in[1];
    const float* nfeat = (const float*)d_in[2];
    const float* feat = (const float*)d_in[3];
    const float* W0 = (const float*)d_in[4];
    const float* g0 = (const float*)d_in[5];
    const float* b0 = (const float*)d_in[6];
    const float* W1 = (const float*)d_in[7];
    const float* g1 = (const float*)d_in[8];
    const float* b1 = (const float*)d_in[9];
    const float* W2 = (const float*)d_in[10];
    const float* g2 = (const float*)d_in[11];
    const float* b2 = (const float*)d_in[12];
    float* out = (float*)d_out;

    char* ws = (char*)d_ws;
    size_t o_idx = 0;                                   // 512 KB
    size_t o_P = o_idx + (size_t)ROWS * 4;              // bf16 P: 1 MB
    size_t o_stats = o_P + (size_t)BB * NN * CC * 2;    // 48 KB
    size_t o_W0p = o_stats + 3 * NSLOT * CO * 2 * 4;    // 24576 B
    size_t o_W2p = o_W0p + 128 * K0P * 2;               // 32768 B
    size_t o_W1s = o_W2p + 16384 * 2;                   // 32768 B
    size_t o_bias = o_W1s + 16384 * 2;                  // 512 B
    size_t o_maxh = (o_bias + 512 + 255) & ~(size_t)255;
    size_t o_minh = o_maxh + (size_t)BB * NN * CO * 4;  // 4 MB each
    size_t o_y0 = o_minh + (size_t)BB * NN * CO * 4;    // bf16: 32 MB
    size_t o_h1 = o_y0 + (size_t)ROWS * CO * 2;         // bf16: 32 MB

    int* idx = (int*)(ws + o_idx);
    unsigned short* P = (unsigned short*)(ws + o_P);
    float* stats0 = (float*)(ws + o_stats);
    float* stats1 = stats0 + NSLOT * CO * 2;
    float* stats2 = stats1 + NSLOT * CO * 2;
    short* W0p = (short*)(ws + o_W0p);
    short* W2p = (short*)(ws + o_W2p);
    short* W1s = (short*)(ws + o_W1s);
    float* bias1 = (float*)(ws + o_bias);
    float* maxh = (float*)(ws + o_maxh);
    float* minh = (float*)(ws + o_minh);
    unsigned short* y0 = (unsigned short*)(ws + o_y0);
    unsigned short* h1 = (unsigned short*)(ws + o_h1);

    k_pre<<<PRE_PREP + PRE_PROD + PRE_BALL, 256, 0, stream>>>(
        anchor, neighbor, feat, nfeat, W0, W2, W0p, W2p, stats0, idx, P);
    k_g0<<<ROWS / 128, 256, 0, stream>>>(anchor, neighbor, P, idx, W0p, y0, stats0);
    k_fold<<<16, 256, 0, stream>>>(stats0, g0, b0, W1, W1s, bias1);
    k_g1<<<ROWS / 128, 256, 0, stream>>>(y0, W1s, bias1, h1, stats1);
    k_g2<<<ROWS / 128, 256, 0, stream>>>(h1, W2p, stats1, g1, b1, maxh, minh, stats2);
    k_out<<<BB * NN * CO / 1024, 256, 0, stream>>>(maxh, minh, stats2, g2, b2, out);
}